// Round 1
// baseline (315.023 us; speedup 1.0000x reference)
//
#include <hip/hip_runtime.h>
#include <hip/hip_bf16.h>

typedef unsigned short u16;
typedef __attribute__((ext_vector_type(4))) short bf16x4;
typedef __attribute__((ext_vector_type(8))) short bf16x8;
typedef __attribute__((ext_vector_type(4))) float f32x4;

#define NB_ 4
#define NT_ 2048
#define NC_ 768
#define NH_ 12
#define ND_ 64
#define NM_ (NB_*NT_)   // 8192 rows

__device__ __forceinline__ u16 f2bf(float f){
  union { float f; unsigned u; } c; c.f = f;
  unsigned u = c.u;
  return (u16)((u + 0x7fffu + ((u>>16)&1u)) >> 16);  // RNE
}

__device__ __forceinline__ bf16x8 cat4(bf16x4 lo, bf16x4 hi){
  return __builtin_shufflevector(lo, hi, 0,1,2,3,4,5,6,7);
}

__device__ __forceinline__ f32x4 mfma16(bf16x8 a, bf16x8 b, f32x4 c){
  return __builtin_amdgcn_mfma_f32_16x16x32_bf16(a, b, c, 0, 0, 0);
}

__device__ __forceinline__ void gload_lds16(const void* g, void* l){
  __builtin_amdgcn_global_load_lds(
    (const __attribute__((address_space(1))) void*)g,
    (__attribute__((address_space(3))) void*)l, 16, 0, 0);
}

// ---------------- cast x (f32 -> bf16), 4 elems/thread ----------------
__global__ __launch_bounds__(256) void cast_f32_bf16_k(
    const float* __restrict__ in, u16* __restrict__ out, int n4){
  int i = blockIdx.x*256 + threadIdx.x;
  if (i >= n4) return;
  float4 v = ((const float4*)in)[i];
  bf16x4 o;
  o[0]=(short)f2bf(v.x); o[1]=(short)f2bf(v.y);
  o[2]=(short)f2bf(v.z); o[3]=(short)f2bf(v.w);
  ((bf16x4*)out)[i] = o;
}

// ------------- transpose + cast: in f32 [R][Cc] -> out bf16 [Cc][R] -------------
__global__ __launch_bounds__(256) void transpose_cast_k(
    const float* __restrict__ in, u16* __restrict__ out, int R, int Cc){
  __shared__ float tile[32][33];
  int tx = threadIdx.x, ty = threadIdx.y;          // 32 x 8
  int c0 = blockIdx.x*32, r0 = blockIdx.y*32;
  #pragma unroll
  for (int j=0;j<32;j+=8) tile[ty+j][tx] = in[(size_t)(r0+ty+j)*Cc + c0+tx];
  __syncthreads();
  #pragma unroll
  for (int j=0;j<32;j+=8) out[(size_t)(c0+ty+j)*R + r0+tx] = f2bf(tile[tx][ty+j]);
}

// ---------------- GEMM: C[128x128] = A[M,K] * BT[N,K]^T  (both bf16 row-major) -------
// MODE 0: qkv -> scatter bf16 to q[B,H,T,D], k[B,H,T,D], v^T[B,H,D,T], bias added
// MODE 1: proj -> f32 out [M][768] + bias
template<int MODE>
__global__ __launch_bounds__(256,2) void gemm128(
  const u16* __restrict__ A, const u16* __restrict__ BT, const float* __restrict__ bias,
  u16* __restrict__ qo, u16* __restrict__ ko, u16* __restrict__ vo,
  float* __restrict__ fo, int Ksz)
{
  __shared__ u16 lds[2][2][128*32];   // [buf][A/B][row*32], 64B rows, 32 KB total
  const int t = threadIdx.x, w = t>>6, l = t&63, g = l>>4, lr = l&15;
  const int brow = blockIdx.y*128, bcol = blockIdx.x*128;
  const int wr = (w>>1)*64, wc = (w&1)*64;

  f32x4 acc[4][4];
  #pragma unroll
  for (int i=0;i<4;i++)
    #pragma unroll
    for (int j=0;j<4;j++) acc[i][j] = (f32x4){0.f,0.f,0.f,0.f};

  // stage: physical 16B chunk (row r, byte pb) <- global row-slice byte (pb ^ swz(r))
  auto stage = [&](int buf, int kt){
    #pragma unroll
    for (int it=0; it<2; ++it){
      int chunk = it*256 + t;           // 512 chunks per tile
      int r = chunk>>2;
      int sb = ((chunk&3)*16) ^ ((r&3)<<4);
      gload_lds16((const char*)(A  + (size_t)(brow+r)*Ksz + kt*32) + sb,
                  (char*)&lds[buf][0][0] + chunk*16);
      gload_lds16((const char*)(BT + (size_t)(bcol+r)*Ksz + kt*32) + sb,
                  (char*)&lds[buf][1][0] + chunk*16);
    }
  };

  // fragment: lane l -> M[row][k], k-halves at logical bytes g*8 and 32+g*8 (same XOR)
  auto ldfrag = [&](const u16* base, int row)->bf16x8{
    const char* rp = (const char*)(base + row*32);
    int sw = (row&3)<<4;
    bf16x4 lo = *(const bf16x4*)(rp + ((g*8) ^ sw));
    bf16x4 hi = *(const bf16x4*)(rp + ((32 + g*8) ^ sw));
    return cat4(lo,hi);
  };

  const int nk = Ksz/32;
  stage(0,0);
  __syncthreads();
  int cur = 0;
  for (int kt=0; kt<nk; ++kt){
    if (kt+1 < nk) stage(cur^1, kt+1);
    const u16* Ab = &lds[cur][0][0];
    const u16* Bb = &lds[cur][1][0];
    bf16x8 af[4], bfr[4];
    #pragma unroll
    for (int mi=0;mi<4;mi++) af[mi]  = ldfrag(Ab, wr + mi*16 + lr);
    #pragma unroll
    for (int nj=0;nj<4;nj++) bfr[nj] = ldfrag(Bb, wc + nj*16 + lr);
    #pragma unroll
    for (int mi=0;mi<4;mi++)
      #pragma unroll
      for (int nj=0;nj<4;nj++)
        acc[mi][nj] = mfma16(af[mi], bfr[nj], acc[mi][nj]);
    __syncthreads();
    cur ^= 1;
  }

  if (MODE == 1){
    #pragma unroll
    for (int nj=0;nj<4;nj++){
      int n = bcol + wc + nj*16 + lr;
      float bs = bias[n];
      #pragma unroll
      for (int mi=0;mi<4;mi++)
        #pragma unroll
        for (int r=0;r<4;r++){
          int m = brow + wr + mi*16 + g*4 + r;
          fo[(size_t)m*NC_ + n] = acc[mi][nj][r] + bs;
        }
    }
  } else {
    const int sec = bcol / NC_;                    // block-uniform (768 % 128 == 0)
    u16* outp = (sec==0) ? qo : (sec==1 ? ko : vo);
    #pragma unroll
    for (int nj=0;nj<4;nj++){
      int n = bcol + wc + nj*16 + lr;
      int cc = n - sec*NC_;
      int h = cc >> 6, d = cc & 63;
      float bs = bias[n];
      #pragma unroll
      for (int mi=0;mi<4;mi++)
        #pragma unroll
        for (int r=0;r<4;r++){
          int m = brow + wr + mi*16 + g*4 + r;
          int bb = m >> 11, tt = m & 2047;
          float v = acc[mi][nj][r] + bs;
          size_t off = (sec==2)
            ? (((size_t)bb*NH_ + h)*ND_ + d)*NT_ + tt     // v stored transposed [B,H,D,T]
            : (((size_t)bb*NH_ + h)*NT_ + tt)*ND_ + d;    // q,k [B,H,T,D]
          outp[off] = f2bf(v);
        }
    }
  }
}

// ---------------- flash attention ----------------
// grid: (B*H)*32 blocks; block = 4 waves, each wave owns 16 q-rows (QBLK=64).
// Swapped QK^T: S^T = mfma(A=K, B=Q) so q is the lane index (l&15) -> softmax
// reduction is shfl_xor(16/32); P (S^T C/D regs) feeds PV A-operand directly.
__global__ __launch_bounds__(256,4) void attn_kernel(
    const u16* __restrict__ qg, const u16* __restrict__ kg,
    const u16* __restrict__ vg, u16* __restrict__ y)
{
  __shared__ u16 kls[2][2048];  // K tile [32 kv][64 d], 128B rows, XOR-swizzled (r&7)
  __shared__ u16 vls[2][2048];  // V^T tile [64 d][32 kv], 64B rows, XOR-swizzled (r&3)
  const int t = threadIdx.x, w = t>>6, l = t&63, g = l>>4, lr = l&15;
  const int bid = blockIdx.x;
  const int qt = bid & 31, bh = bid >> 5;
  const int bb = bh / NH_, hh = bh % NH_;
  const u16* qp = qg + (size_t)bh*NT_*ND_;
  const u16* kp = kg + (size_t)bh*NT_*ND_;
  const u16* vp = vg + (size_t)bh*ND_*NT_;
  const int qbase = qt*64;
  const int qrow = qbase + w*16 + lr;   // this lane's q (column of S^T)

  // Q B-operand fragments (hoisted to registers): Qf[dc], d-chunk dc of 32
  bf16x8 Qf[2];
  {
    const u16* qr = qp + (size_t)qrow*ND_;
    #pragma unroll
    for (int dc=0; dc<2; ++dc){
      bf16x4 lo = *(const bf16x4*)(qr + dc*32 + g*4);
      bf16x4 hi = *(const bf16x4*)(qr + dc*32 + 16 + g*4);
      Qf[dc] = cat4(lo,hi);
    }
  }

  f32x4 yacc[4];
  #pragma unroll
  for (int i=0;i<4;i++) yacc[i] = (f32x4){0.f,0.f,0.f,0.f};
  float mrun = -1e30f, lsum = 0.f;
  const int nc = 2*qt + 2;              // causal: kv chunks of 32 up to qbase+63

  auto stage = [&](int buf, int c){
    int kv0 = c*32;
    int rk = t>>3, pbk = (t&7)*16;
    gload_lds16((const char*)(kp + (size_t)(kv0+rk)*ND_) + (pbk ^ ((rk&7)<<4)),
                (char*)&kls[buf][0] + t*16);
    int rv = t>>2, pbv = (t&3)*16;
    gload_lds16((const char*)(vp + (size_t)rv*NT_ + kv0) + (pbv ^ ((rv&3)<<4)),
                (char*)&vls[buf][0] + t*16);
  };

  stage(0,0);
  __syncthreads();
  int cur = 0;
  const float sc = 0.125f * 1.44269504088896340736f;   // (1/sqrt(64)) * log2(e)
  for (int c=0; c<nc; ++c){
    if (c+1 < nc) stage(cur^1, c+1);
    const u16* Kb = &kls[cur][0];
    const u16* Vb = &vls[cur][0];
    const int kv0 = c*32;

    // S^T = K * Q^T  (two 16-kv blocks, accumulate over d=0..63)
    f32x4 s0 = (f32x4){0.f,0.f,0.f,0.f}, s1 = s0;
    #pragma unroll
    for (int dc=0; dc<2; ++dc){
      {
        int row = lr;                               // kv block 0
        const char* rp = (const char*)(Kb + row*64);
        int sw = (row&7)<<4;
        bf16x4 lo = *(const bf16x4*)(rp + ((dc*64 + g*8) ^ sw));
        bf16x4 hi = *(const bf16x4*)(rp + ((dc*64 + 32 + g*8) ^ sw));
        s0 = mfma16(cat4(lo,hi), Qf[dc], s0);
      }
      {
        int row = 16 + lr;                          // kv block 1
        const char* rp = (const char*)(Kb + row*64);
        int sw = (row&7)<<4;
        bf16x4 lo = *(const bf16x4*)(rp + ((dc*64 + g*8) ^ sw));
        bf16x4 hi = *(const bf16x4*)(rp + ((dc*64 + 32 + g*8) ^ sw));
        s1 = mfma16(cat4(lo,hi), Qf[dc], s1);
      }
    }

    // online softmax (exp2 domain); lane holds kv = kv0 + {0,16}+g*4+r for q = qrow
    float sv[8]; float mloc = -1e30f;
    #pragma unroll
    for (int r=0;r<4;r++){
      int kva = kv0 + g*4 + r;
      float xa = s0[r]*sc;  xa = (kva <= qrow) ? xa : -1e30f;
      sv[r] = xa;  mloc = fmaxf(mloc, xa);
      int kvb = kv0 + 16 + g*4 + r;
      float xb = s1[r]*sc;  xb = (kvb <= qrow) ? xb : -1e30f;
      sv[4+r] = xb;  mloc = fmaxf(mloc, xb);
    }
    mloc = fmaxf(mloc, __shfl_xor(mloc,16));
    mloc = fmaxf(mloc, __shfl_xor(mloc,32));
    float mnew = fmaxf(mrun, mloc);
    float fsc = exp2f(mrun - mnew);
    mrun = mnew;

    float ps = 0.f;
    bf16x8 pa;
    #pragma unroll
    for (int i=0;i<8;i++){
      float p = exp2f(sv[i] - mnew);
      ps += p;
      pa[i] = (short)f2bf(p);
    }
    ps += __shfl_xor(ps,16);
    ps += __shfl_xor(ps,32);
    lsum = lsum*fsc + ps;

    // rescale O; yacc lane rows are q_local = g*4+r -> fetch that q's factor
    #pragma unroll
    for (int r=0;r<4;r++){
      float fr = __shfl(fsc, g*4 + r);
      #pragma unroll
      for (int nb=0;nb<4;nb++) yacc[nb][r] *= fr;
    }

    // PV: yacc[nb] += P[16q x 32kv] * V[32kv x 16d]
    #pragma unroll
    for (int nb=0;nb<4;nb++){
      int row = nb*16 + lr;                         // V^T row = d
      const char* rp = (const char*)(Vb + row*32);
      int sw = (row&3)<<4;
      bf16x4 lo = *(const bf16x4*)(rp + ((g*8) ^ sw));
      bf16x4 hi = *(const bf16x4*)(rp + ((32 + g*8) ^ sw));
      yacc[nb] = mfma16(pa, cat4(lo,hi), yacc[nb]);
    }
    __syncthreads();
    cur ^= 1;
  }

  // epilogue: y[b, t, h*64+d] = yacc / lsum(q)
  #pragma unroll
  for (int r=0;r<4;r++){
    float inv = 1.f / __shfl(lsum, g*4 + r);
    int tt = qbase + w*16 + g*4 + r;
    u16* yr = y + ((size_t)bb*NT_ + tt)*NC_ + hh*ND_;
    #pragma unroll
    for (int nb=0;nb<4;nb++)
      yr[nb*16 + lr] = f2bf(yacc[nb][r] * inv);
  }
}

// ---------------- launch ----------------
extern "C" void kernel_launch(void* const* d_in, const int* in_sizes, int n_in,
                              void* d_out, int out_size, void* d_ws, size_t ws_size,
                              hipStream_t stream) {
  const float* x  = (const float*)d_in[0];
  const float* wa = (const float*)d_in[1];
  const float* ba = (const float*)d_in[2];
  const float* wp = (const float*)d_in[3];
  const float* bp = (const float*)d_in[4];
  float* out = (float*)d_out;

  char* ws = (char*)d_ws;
  const size_t szXB = (size_t)NM_*NC_*2;        // 12,582,912
  const size_t szWA = (size_t)3*NC_*NC_*2;      //  3,538,944
  const size_t szWP = (size_t)NC_*NC_*2;        //  1,179,648
  const size_t szQ  = szXB;
  u16* xb  = (u16*)(ws);
  u16* wat = (u16*)(ws + szXB);
  u16* wpt = (u16*)(ws + szXB + szWA);
  u16* qb  = (u16*)(ws + szXB + szWA + szWP);
  u16* kb  = (u16*)((char*)qb + szQ);
  u16* vb  = (u16*)((char*)kb + szQ);
  u16* yb  = xb;    // reuse x-slot: attn writes y after qkv GEMM consumed xb

  // 1) casts / transposes
  cast_f32_bf16_k<<<dim3((NM_*NC_/4 + 255)/256), dim3(256), 0, stream>>>(x, xb, NM_*NC_/4);
  transpose_cast_k<<<dim3(3*NC_/32, NC_/32), dim3(32,8), 0, stream>>>(wa, wat, NC_, 3*NC_);
  transpose_cast_k<<<dim3(NC_/32, NC_/32), dim3(32,8), 0, stream>>>(wp, wpt, NC_, NC_);
  // 2) qkv = x @ w_attn + b_attn  -> q,k,v^T scattered
  gemm128<0><<<dim3(3*NC_/128, NM_/128), dim3(256), 0, stream>>>(
      xb, wat, ba, qb, kb, vb, (float*)nullptr, NC_);
  // 3) flash attention -> y [B,T,C] bf16
  attn_kernel<<<dim3(NB_*NH_*(NT_/64)), dim3(256), 0, stream>>>(qb, kb, vb, yb);
  // 4) out = y @ w_proj + b_proj (f32)
  gemm128<1><<<dim3(NC_/128, NM_/128), dim3(256), 0, stream>>>(
      yb, wpt, bp, (u16*)nullptr, (u16*)nullptr, (u16*)nullptr, out, NC_);
}

// Round 3
// 205.380 us; speedup vs baseline: 1.5339x; 1.5339x over previous
//
#include <hip/hip_runtime.h>
#include <hip/hip_bf16.h>

typedef unsigned short u16;
typedef __attribute__((ext_vector_type(4))) short bf16x4;
typedef __attribute__((ext_vector_type(8))) short bf16x8;
typedef __attribute__((ext_vector_type(4))) float f32x4;
typedef __attribute__((ext_vector_type(16))) float f32x16;

#define NB_ 4
#define NT_ 2048
#define NC_ 768
#define NH_ 12
#define ND_ 64
#define NM_ (NB_*NT_)   // 8192 rows

// 1/sqrt(64) * log2(e): folded into q at the QKV epilogue -> attention runs in exp2 domain
#define SCQ_ 0.18033688011112042f

__device__ __forceinline__ u16 f2bf(float f){
  union { float f; unsigned u; } c; c.f = f;
  unsigned u = c.u;
  return (u16)((u + 0x7fffu + ((u>>16)&1u)) >> 16);  // RNE
}

__device__ __forceinline__ unsigned pkbf(float a, float b){
  __hip_bfloat162 h = __float22bfloat162_rn(make_float2(a,b));  // v_cvt_pk_bf16_f32
  union { __hip_bfloat162 h; unsigned u; } c; c.h = h; return c.u;
}

__device__ __forceinline__ bf16x8 cat4(bf16x4 lo, bf16x4 hi){
  return __builtin_shufflevector(lo, hi, 0,1,2,3,4,5,6,7);
}

__device__ __forceinline__ f32x4 mfma16(bf16x8 a, bf16x8 b, f32x4 c){
  return __builtin_amdgcn_mfma_f32_16x16x32_bf16(a, b, c, 0, 0, 0);
}
__device__ __forceinline__ f32x16 mfma32(bf16x8 a, bf16x8 b, f32x16 c){
  return __builtin_amdgcn_mfma_f32_32x32x16_bf16(a, b, c, 0, 0, 0);
}

__device__ __forceinline__ void gload_lds16(const void* g, void* l){
  __builtin_amdgcn_global_load_lds(
    (const __attribute__((address_space(1))) void*)g,
    (__attribute__((address_space(3))) void*)l, 16, 0, 0);
}

// ---------------- cast x (f32 -> bf16), 4 elems/thread ----------------
__global__ __launch_bounds__(256) void cast_f32_bf16_k(
    const float* __restrict__ in, u16* __restrict__ out, int n4){
  int i = blockIdx.x*256 + threadIdx.x;
  if (i >= n4) return;
  float4 v = ((const float4*)in)[i];
  bf16x4 o;
  o[0]=(short)f2bf(v.x); o[1]=(short)f2bf(v.y);
  o[2]=(short)f2bf(v.z); o[3]=(short)f2bf(v.w);
  ((bf16x4*)out)[i] = o;
}

// ------------- transpose + cast: in f32 [R][Cc] -> out bf16 [Cc][R] -------------
__global__ __launch_bounds__(256) void transpose_cast_k(
    const float* __restrict__ in, u16* __restrict__ out, int R, int Cc){
  __shared__ float tile[32][33];
  int tx = threadIdx.x, ty = threadIdx.y;          // 32 x 8
  int c0 = blockIdx.x*32, r0 = blockIdx.y*32;
  #pragma unroll
  for (int j=0;j<32;j+=8) tile[ty+j][tx] = in[(size_t)(r0+ty+j)*Cc + c0+tx];
  __syncthreads();
  #pragma unroll
  for (int j=0;j<32;j+=8) out[(size_t)(c0+ty+j)*R + r0+tx] = f2bf(tile[tx][ty+j]);
}

// ---------------- GEMM: C[128x128] = A[M,K] * BT[N,K]^T  (both bf16 row-major) -------
// MODE 0: qkv -> scatter bf16 to q*scale [B,H,T,D], k [B,H,T,D], v^T [B,H,D,T], bias added
// MODE 1: proj -> f32 out [M][768] + bias
template<int MODE>
__global__ __launch_bounds__(256,2) void gemm128(
  const u16* __restrict__ A, const u16* __restrict__ BT, const float* __restrict__ bias,
  u16* __restrict__ qo, u16* __restrict__ ko, u16* __restrict__ vo,
  float* __restrict__ fo, int Ksz)
{
  __shared__ u16 lds[2][2][128*32];   // [buf][A/B][row*32], 64B rows, 32 KB total
  const int t = threadIdx.x, w = t>>6, l = t&63, g = l>>4, lr = l&15;
  const int brow = blockIdx.y*128, bcol = blockIdx.x*128;
  const int wr = (w>>1)*64, wc = (w&1)*64;

  f32x4 acc[4][4];
  #pragma unroll
  for (int i=0;i<4;i++)
    #pragma unroll
    for (int j=0;j<4;j++) acc[i][j] = (f32x4){0.f,0.f,0.f,0.f};

  auto stage = [&](int buf, int kt){
    #pragma unroll
    for (int it=0; it<2; ++it){
      int chunk = it*256 + t;           // 512 chunks per tile
      int r = chunk>>2;
      int sb = ((chunk&3)*16) ^ ((r&3)<<4);
      gload_lds16((const char*)(A  + (size_t)(brow+r)*Ksz + kt*32) + sb,
                  (char*)&lds[buf][0][0] + chunk*16);
      gload_lds16((const char*)(BT + (size_t)(bcol+r)*Ksz + kt*32) + sb,
                  (char*)&lds[buf][1][0] + chunk*16);
    }
  };

  auto ldfrag = [&](const u16* base, int row)->bf16x8{
    const char* rp = (const char*)(base + row*32);
    int sw = (row&3)<<4;
    bf16x4 lo = *(const bf16x4*)(rp + ((g*8) ^ sw));
    bf16x4 hi = *(const bf16x4*)(rp + ((32 + g*8) ^ sw));
    return cat4(lo,hi);
  };

  const int nk = Ksz/32;
  stage(0,0);
  __syncthreads();
  int cur = 0;
  for (int kt=0; kt<nk; ++kt){
    if (kt+1 < nk) stage(cur^1, kt+1);
    const u16* Ab = &lds[cur][0][0];
    const u16* Bb = &lds[cur][1][0];
    bf16x8 af[4], bfr[4];
    #pragma unroll
    for (int mi=0;mi<4;mi++) af[mi]  = ldfrag(Ab, wr + mi*16 + lr);
    #pragma unroll
    for (int nj=0;nj<4;nj++) bfr[nj] = ldfrag(Bb, wc + nj*16 + lr);
    #pragma unroll
    for (int mi=0;mi<4;mi++)
      #pragma unroll
      for (int nj=0;nj<4;nj++)
        acc[mi][nj] = mfma16(af[mi], bfr[nj], acc[mi][nj]);
    __syncthreads();
    cur ^= 1;
  }

  if (MODE == 1){
    #pragma unroll
    for (int nj=0;nj<4;nj++){
      int n = bcol + wc + nj*16 + lr;
      float bs = bias[n];
      #pragma unroll
      for (int mi=0;mi<4;mi++)
        #pragma unroll
        for (int r=0;r<4;r++){
          int m = brow + wr + mi*16 + g*4 + r;
          fo[(size_t)m*NC_ + n] = acc[mi][nj][r] + bs;
        }
    }
  } else {
    const int sec = bcol / NC_;                    // block-uniform (768 % 128 == 0)
    u16* outp = (sec==0) ? qo : (sec==1 ? ko : vo);
    #pragma unroll
    for (int nj=0;nj<4;nj++){
      int n = bcol + wc + nj*16 + lr;
      int cc = n - sec*NC_;
      int h = cc >> 6, d = cc & 63;
      float bs = bias[n];
      #pragma unroll
      for (int mi=0;mi<4;mi++)
        #pragma unroll
        for (int r=0;r<4;r++){
          int m = brow + wr + mi*16 + g*4 + r;
          int bb = m >> 11, tt = m & 2047;
          float v = acc[mi][nj][r] + bs;
          if (sec == 0) v *= SCQ_;                 // pre-scale q for exp2-domain attn
          size_t off = (sec==2)
            ? (((size_t)bb*NH_ + h)*ND_ + d)*NT_ + tt     // v stored transposed [B,H,D,T]
            : (((size_t)bb*NH_ + h)*NT_ + tt)*ND_ + d;    // q,k [B,H,T,D]
          outp[off] = f2bf(v);
        }
    }
  }
}

// ---------------- flash attention v2: 32x32x16 MFMA, lane-local softmax ----------------
// QBLK=64 (2 waves x 32 q), KVBLK=64, double-buffered K/V LDS (32 KB).
// Swapped S^T = mfma(A=K rows, B=Q): C/D col = q = lane&31 -> softmax state lane-local.
// 32x32 C/D row map (r&3)+8*(r>>2)+4*(l>>5) == B-operand k map -> P feeds PV in-lane.
__global__ __launch_bounds__(128,2) void attn_kernel(
    const u16* __restrict__ qg, const u16* __restrict__ kg,
    const u16* __restrict__ vg, u16* __restrict__ y)
{
  __shared__ u16 kls[2][64*64];   // K tile [64 kv][64 d], 128B rows, XOR-swizzled (r&7)<<4
  __shared__ u16 vls[2][64*64];   // V^T tile [64 d][64 kv], same swizzle
  const int t = threadIdx.x, w = t>>6, l = t&63;
  const int lq = l&31, h = l>>5;
  const int bid = blockIdx.x;
  const int qt = 31 - (bid/48);   // heaviest q-tiles first (load balance)
  const int bh = bid % 48;
  const int bb = bh / NH_, hh = bh % NH_;
  const u16* qp = qg + (size_t)bh*NT_*ND_;
  const u16* kp = kg + (size_t)bh*NT_*ND_;
  const u16* vp = vg + (size_t)bh*ND_*NT_;
  const int qb = qt*64;
  const int qmin = qb + w*32;
  const int q = qmin + lq;        // this lane's q row (column of S^T)

  // Q B-operand frags: k = d = ks*16 + 4h + (i&3) + 8*(i>>2)
  bf16x8 Qf[4];
  {
    const u16* qr = qp + (size_t)q*ND_;
    #pragma unroll
    for (int ks=0; ks<4; ++ks){
      bf16x4 lo = *(const bf16x4*)(qr + ks*16 + 4*h);
      bf16x4 hi = *(const bf16x4*)(qr + ks*16 + 8 + 4*h);
      Qf[ks] = cat4(lo,hi);
    }
  }

  f32x16 o0, o1;                  // O^T acc: col=q, row d = (r&3)+8*(r>>2)+4h (+32 for o1)
  #pragma unroll
  for (int r=0;r<16;r++){ o0[r]=0.f; o1[r]=0.f; }
  float mrun = -3e38f, lsum = 0.f;
  const int nc = qt + 1;          // causal 64-kv chunks

  auto stage = [&](int buf, int c){
    int kv0 = c*64;
    #pragma unroll
    for (int it=0; it<4; ++it){
      int cid = it*128 + t;       // 512 x 16B per tile
      int r = cid>>3, s = cid&7;
      int sb = (s*16) ^ ((r&7)<<4);
      gload_lds16((const char*)(kp + (size_t)(kv0+r)*ND_) + sb,
                  (char*)&kls[buf][0] + cid*16);
      gload_lds16((const char*)(vp + (size_t)r*NT_ + kv0) + sb,
                  (char*)&vls[buf][0] + cid*16);
    }
  };

  // A-frag read (K or V^T): row-major 128B rows; lane row = base+lq, k-halves at
  // logical bytes ks*32+8h and ks*32+16+8h, slot-XOR (row&7)
  auto ldAB = [&](const u16* base, int row, int ks)->bf16x8{
    const char* rp = (const char*)base + row*128;
    int sw = (row&7)<<4;
    bf16x4 lo = *(const bf16x4*)(rp + (((ks*32)    ^ sw) + 8*h));
    bf16x4 hi = *(const bf16x4*)(rp + (((ks*32+16) ^ sw) + 8*h));
    return cat4(lo,hi);
  };

  stage(0,0);
  __syncthreads();
  int cur = 0;
  for (int c=0; c<nc; ++c){
    if (c+1 < nc) stage(cur^1, c+1);
    const u16* Kb = &kls[cur][0];
    const u16* Vb = &vls[cur][0];
    const int kv0 = c*64;

    // S^T (64 kv x 32 q), q pre-scaled -> exp2 domain
    f32x16 s0, s1;
    #pragma unroll
    for (int r=0;r<16;r++){ s0[r]=0.f; s1[r]=0.f; }
    #pragma unroll
    for (int ks=0; ks<4; ++ks){
      s0 = mfma32(ldAB(Kb, lq,      ks), Qf[ks], s0);
      s1 = mfma32(ldAB(Kb, 32 + lq, ks), Qf[ks], s1);
    }

    // causal mask: only the diagonal chunk is partial (wave-uniform branch)
    if (kv0 + 63 > qmin){
      #pragma unroll
      for (int r=0;r<16;r++){
        int kva = kv0 + (r&3) + 8*(r>>2) + 4*h;
        s0[r] = (kva      <= q) ? s0[r] : -3e38f;
        s1[r] = (kva + 32 <= q) ? s1[r] : -3e38f;
      }
    }

    // row max: lane-local 32, then cross-half swap via shfl_xor(32)
    float m0 = s0[0];
    #pragma unroll
    for (int r=1;r<16;r++) m0 = fmaxf(m0, s0[r]);
    #pragma unroll
    for (int r=0;r<16;r++) m0 = fmaxf(m0, s1[r]);
    m0 = fmaxf(m0, __shfl_xor(m0, 32));

    // defer-max (T13): rescale only when max grew past threshold
    if (__any(m0 > mrun + 8.f)){
      float mnew = fmaxf(mrun, m0);
      float fsc = exp2f(mrun - mnew);
      mrun = mnew;
      lsum *= fsc;
      #pragma unroll
      for (int r=0;r<16;r++){ o0[r]*=fsc; o1[r]*=fsc; }
    }

    // P = exp2(s - mrun); pack pairs (v_cvt_pk_bf16_f32); sum lane-local
    float ps = 0.f;
    union { unsigned wd[16]; bf16x8 v[4]; } pf;
    #pragma unroll
    for (int j=0;j<8;j++){
      float a = exp2f(s0[2*j] - mrun), b = exp2f(s0[2*j+1] - mrun);
      ps += a + b;
      pf.wd[j] = pkbf(a,b);
    }
    #pragma unroll
    for (int j=0;j<8;j++){
      float a = exp2f(s1[2*j] - mrun), b = exp2f(s1[2*j+1] - mrun);
      ps += a + b;
      pf.wd[8+j] = pkbf(a,b);
    }
    ps += __shfl_xor(ps, 32);
    lsum += ps;

    // PV: O^T += V^T * P^T ; P regs feed B-operand directly (in-lane)
    #pragma unroll
    for (int j=0;j<4;j++){
      o0 = mfma32(ldAB(Vb, lq,      j), pf.v[j], o0);
      o1 = mfma32(ldAB(Vb, 32 + lq, j), pf.v[j], o1);
    }
    __syncthreads();
    cur ^= 1;
  }

  // epilogue: y[b][t=q][hh*64+d] = O^T[d][q] / lsum  (8B packed stores)
  float inv = 1.f / lsum;
  u16* yr = y + ((size_t)bb*NT_ + q)*NC_ + hh*ND_;
  #pragma unroll
  for (int db=0; db<2; ++db){
    #pragma unroll
    for (int g2=0; g2<4; ++g2){
      float e0 = (db ? o1[g2*4+0] : o0[g2*4+0]) * inv;
      float e1 = (db ? o1[g2*4+1] : o0[g2*4+1]) * inv;
      float e2 = (db ? o1[g2*4+2] : o0[g2*4+2]) * inv;
      float e3 = (db ? o1[g2*4+3] : o0[g2*4+3]) * inv;
      unsigned w0 = pkbf(e0,e1), w1 = pkbf(e2,e3);
      int d0 = db*32 + g2*8 + 4*h;
      *(uint2*)(yr + d0) = make_uint2(w0, w1);
    }
  }
}

// ---------------- launch ----------------
extern "C" void kernel_launch(void* const* d_in, const int* in_sizes, int n_in,
                              void* d_out, int out_size, void* d_ws, size_t ws_size,
                              hipStream_t stream) {
  const float* x  = (const float*)d_in[0];
  const float* wa = (const float*)d_in[1];
  const float* ba = (const float*)d_in[2];
  const float* wp = (const float*)d_in[3];
  const float* bp = (const float*)d_in[4];
  float* out = (float*)d_out;

  char* ws = (char*)d_ws;
  const size_t szXB = (size_t)NM_*NC_*2;        // 12,582,912
  const size_t szWA = (size_t)3*NC_*NC_*2;      //  3,538,944
  const size_t szWP = (size_t)NC_*NC_*2;        //  1,179,648
  const size_t szQ  = szXB;
  u16* xb  = (u16*)(ws);
  u16* wat = (u16*)(ws + szXB);
  u16* wpt = (u16*)(ws + szXB + szWA);
  u16* qb  = (u16*)(ws + szXB + szWA + szWP);
  u16* kb  = (u16*)((char*)qb + szQ);
  u16* vb  = (u16*)((char*)kb + szQ);
  u16* yb  = xb;    // reuse x-slot: attn writes y after qkv GEMM consumed xb

  // 1) casts / transposes
  cast_f32_bf16_k<<<dim3((NM_*NC_/4 + 255)/256), dim3(256), 0, stream>>>(x, xb, NM_*NC_/4);
  transpose_cast_k<<<dim3(3*NC_/32, NC_/32), dim3(32,8), 0, stream>>>(wa, wat, NC_, 3*NC_);
  transpose_cast_k<<<dim3(NC_/32, NC_/32), dim3(32,8), 0, stream>>>(wp, wpt, NC_, NC_);
  // 2) qkv = x @ w_attn + b_attn  -> q*scale, k, v^T scattered
  gemm128<0><<<dim3(3*NC_/128, NM_/128), dim3(256), 0, stream>>>(
      xb, wat, ba, qb, kb, vb, (float*)nullptr, NC_);
  // 3) flash attention -> y [B,T,C] bf16
  attn_kernel<<<dim3(NB_*NH_*(NT_/64)), dim3(128), 0, stream>>>(qb, kb, vb, yb);
  // 4) out = y @ w_proj + b_proj (f32)
  gemm128<1><<<dim3(NC_/128, NM_/128), dim3(256), 0, stream>>>(
      yb, wpt, bp, (u16*)nullptr, (u16*)nullptr, (u16*)nullptr, out, NC_);
}